// Round 4
// baseline (396.074 us; speedup 1.0000x reference)
//
#include <hip/hip_runtime.h>
#include <hip/hip_bf16.h>

#define NN 2048

typedef __attribute__((ext_vector_type(4))) float f32x4;
typedef __attribute__((ext_vector_type(8))) short bf16x8;

__device__ __forceinline__ unsigned short f2bf(float f) {
  __hip_bfloat16 h = __float2bfloat16(f);
  return __builtin_bit_cast(unsigned short, h);
}
__device__ __forceinline__ unsigned int pk2(float a, float b) {
  return (unsigned int)f2bf(a) | ((unsigned int)f2bf(b) << 16);
}
__device__ __forceinline__ void gld_lds16(const void* g, void* l) {
  __builtin_amdgcn_global_load_lds(
      (const __attribute__((address_space(1))) unsigned int*)g,
      (__attribute__((address_space(3))) unsigned int*)l, 16, 0, 0);
}
// nontemporal f32x4 load (A is a read-once stream; keep it out of L2's way)
__device__ __forceinline__ f32x4 ntl(const float* p) {
  return __builtin_nontemporal_load((const f32x4*)p);
}

// f32 (R x C) -> bf16 (C x R), batched via blockIdx.z
__global__ void k_tr_cvt(const float* __restrict__ src, unsigned short* __restrict__ dst,
                         int R, int C) {
  int b = blockIdx.z;
  src += (size_t)b * R * C;
  dst += (size_t)b * R * C;
  __shared__ float tile[32][33];
  int r0 = blockIdx.x * 32, c0 = blockIdx.y * 32;
  int t = threadIdx.x;
  int r = t >> 3, c4 = (t & 7) << 2;
  float4 v = *(const float4*)(src + (size_t)(r0 + r) * C + c0 + c4);
  tile[r][c4 + 0] = v.x; tile[r][c4 + 1] = v.y; tile[r][c4 + 2] = v.z; tile[r][c4 + 3] = v.w;
  __syncthreads();
  ushort4 o;
  o.x = f2bf(tile[c4 + 0][r]); o.y = f2bf(tile[c4 + 1][r]);
  o.z = f2bf(tile[c4 + 2][r]); o.w = f2bf(tile[c4 + 3][r]);
  *(ushort4*)(dst + (size_t)(c0 + r) * R + r0 + c4) = o;
}

#define ASP(bf) (As0 + (bf) * (BM * 64))
#define BSP(bf) (Bs0 + (bf) * (NCOLS * 64))
#define RED(sx, rl, w) redp[(((sx) * BM) + (rl)) * 4 + (w)]

// One K-step: issue A loads for kt+2 (nt), stage B kt+1 via global_load_lds,
// cvt A regs (loaded 2 steps ago) into As[nxt], MFMA current tile, barrier.
#define AGG_STEP(KT, AREGC, AREGN, CUR)                                        \
  {                                                                            \
    const int kt_ = (KT);                                                      \
    if (kt_ < NKT - 2) {                                                       \
      const float* p_ = apb + (size_t)(kt_ + 2) * 64;                          \
      _Pragma("unroll") for (int j = 0; j < F4; ++j)                           \
          AREGN[j] = ntl(p_ + j * 4);                                          \
    }                                                                          \
    if (kt_ < NKT - 1) {                                                       \
      _Pragma("unroll") for (int i = 0; i < NF; ++i) {                         \
        int jj = i * 512 + t;                                                  \
        int n_ = jj >> 3, s_ = jj & 7, sp_ = s_ ^ (n_ & 7);                    \
        gld_lds16(BTb + (size_t)n_ * NN + (size_t)(kt_ + 1) * 64 + sp_ * 8,    \
                  BSP((CUR) ^ 1) + (i * 512 + wid * 64) * 8);                  \
      }                                                                        \
      _Pragma("unroll") for (int i = 0; i < U4W; ++i) {                        \
        uint4 w_;                                                              \
        w_.x = pk2(AREGC[2 * i][0], AREGC[2 * i][1]);                          \
        w_.y = pk2(AREGC[2 * i][2], AREGC[2 * i][3]);                          \
        w_.z = pk2(AREGC[2 * i + 1][0], AREGC[2 * i + 1][1]);                  \
        w_.w = pk2(AREGC[2 * i + 1][2], AREGC[2 * i + 1][3]);                  \
        int s_ = ak * U4W + i, sp_ = s_ ^ (ar & 7);                            \
        *(uint4*)(ASP((CUR) ^ 1) + (ar * 8 + sp_) * 8) = w_;                   \
      }                                                                        \
    }                                                                          \
    _Pragma("unroll") for (int kh = 0; kh < 2; ++kh) {                         \
      bf16x8 af[MI], bfr[NF];                                                  \
      _Pragma("unroll") for (int mi = 0; mi < MI; ++mi) {                      \
        int row = wr * (BM / 2) + mi * 16 + lr;                                \
        int sp_ = (kh * 4 + q) ^ (row & 7);                                    \
        af[mi] = *(const bf16x8*)(ASP(CUR) + (row * 8 + sp_) * 8);             \
      }                                                                        \
      _Pragma("unroll") for (int ni = 0; ni < NF; ++ni) {                      \
        int brow = wc * WN + ni * 16 + lr;                                     \
        int sp_ = (kh * 4 + q) ^ (brow & 7);                                   \
        bfr[ni] = *(const bf16x8*)(BSP(CUR) + (brow * 8 + sp_) * 8);           \
      }                                                                        \
      _Pragma("unroll") for (int mi = 0; mi < MI; ++mi)                        \
        _Pragma("unroll") for (int ni = 0; ni < NF; ++ni)                      \
          acc[mi][ni] = __builtin_amdgcn_mfma_f32_16x16x32_bf16(               \
              af[mi], bfr[ni], acc[mi][ni], 0, 0, 0);                          \
    }                                                                          \
    __syncthreads();                                                           \
  }

// Fused: T = A[b] (NNxNN f32) @ B[b] (BT given, NCOLS x NN bf16), then
// out = relu(LN(T @ W + bias)), W^T given (256 x NCOLS bf16).
// MODE 0: write out^T (b,256,NN). MODE 1: per-block column partials -> gpart.
// 512 threads, 8 waves (2 wr x 4 wc). Tile BM x NCOLS, BK=64.
template <int BM, int NCOLS, int MODE>
__global__ __launch_bounds__(512, 4) void k_agg_fused(
    const float* __restrict__ A, const unsigned short* __restrict__ BT,
    const unsigned short* __restrict__ WT, const float* __restrict__ bias,
    const float* __restrict__ gamma, const float* __restrict__ beta,
    unsigned short* __restrict__ HTout, float* __restrict__ gpart) {
  constexpr int WN = NCOLS / 4;       // wave n-width (main loop)
  constexpr int NF = NCOLS / 64;      // b-frag count / B-stage iters
  constexpr int MI = BM / 32;         // m-frag count
  constexpr int NKT = NN / 64;        // 32 K-steps
  constexpr int FIN = NCOLS;          // K of fused linear
  constexpr int NQT = FIN / 64;       // epilogue K-quarters
  constexpr int TPR = 512 / BM;       // threads per A row
  constexpr int FPT = BM * 64 / 512;  // f32 per thread per K-step
  constexpr int F4 = FPT / 4;         // float4 loads per thread
  constexpr int U4W = F4 / 2;         // uint4 LDS writes per thread
  constexpr int NMB = NN / BM;        // m-blocks per batch
  constexpr int AS_B = 2 * BM * 64 * 2;
  constexpr int BS_B = 2 * NCOLS * 64 * 2;

  __shared__ __align__(16) char smem[AS_B + BS_B];
  unsigned short* As0 = (unsigned short*)smem;
  unsigned short* Bs0 = (unsigned short*)(smem + AS_B);
  float* redp = (float*)smem;  // overlay on As; live only after extra barrier

  // XCD-aware swizzle: all blocks sharing one BT panel land on one XCD's L2.
  int L = blockIdx.x + gridDim.x * blockIdx.z;
  int xcd = L & 7, slot = L >> 3;
  int mb = slot % NMB;
  int b = xcd + 8 * (slot / NMB);
  int m0 = mb * BM;

  const float* Ab = A + (size_t)b * NN * NN;
  const unsigned short* BTb = BT + (size_t)b * (size_t)NCOLS * NN;
  int t = threadIdx.x, lane = t & 63, wid = t >> 6;
  int wr = wid >> 2, wc = wid & 3;
  int q = lane >> 4, lr = lane & 15;
  int ar = t / TPR, ak = t % TPR;
  const float* apb = Ab + (size_t)(m0 + ar) * NN + ak * FPT;

  f32x4 acc[MI][NF] = {};
  f32x4 aregA[F4], aregB[F4];

  // prologue: tile0 -> buf0; issue tile1 A loads
  {
#pragma unroll
    for (int j = 0; j < F4; ++j) aregA[j] = ntl(apb + j * 4);
#pragma unroll
    for (int i = 0; i < NF; ++i) {
      int jj = i * 512 + t;
      int n = jj >> 3, s = jj & 7, sp = s ^ (n & 7);
      gld_lds16(BTb + (size_t)n * NN + sp * 8, BSP(0) + (i * 512 + wid * 64) * 8);
    }
#pragma unroll
    for (int i = 0; i < U4W; ++i) {
      uint4 w;
      w.x = pk2(aregA[2 * i][0], aregA[2 * i][1]);
      w.y = pk2(aregA[2 * i][2], aregA[2 * i][3]);
      w.z = pk2(aregA[2 * i + 1][0], aregA[2 * i + 1][1]);
      w.w = pk2(aregA[2 * i + 1][2], aregA[2 * i + 1][3]);
      int s = ak * U4W + i, sp = s ^ (ar & 7);
      *(uint4*)(ASP(0) + (ar * 8 + sp) * 8) = w;
    }
#pragma unroll
    for (int j = 0; j < F4; ++j) aregB[j] = ntl(apb + 64 + j * 4);
  }
  __syncthreads();

  for (int k2 = 0; k2 < NKT / 2; ++k2) {
    AGG_STEP(2 * k2, aregB, aregA, 0);
    AGG_STEP(2 * k2 + 1, aregA, aregB, 1);
  }

  // ---- epilogue: T(BM x FIN) -> bf16 Hs in LDS (swizzled) ----
  unsigned short* Hs = (NCOLS == 128) ? As0 : Bs0;
  unsigned short* Ws = (NCOLS == 128) ? Bs0 : Bs0 + NCOLS * 64;
#pragma unroll
  for (int mi = 0; mi < MI; ++mi) {
#pragma unroll
    for (int ni = 0; ni < NF; ++ni) {
#pragma unroll
      for (int j = 0; j < 4; ++j) {
        int row = wr * (BM / 2) + mi * 16 + q * 4 + j;
        int col = wc * WN + ni * 16 + lr;
        int sp = (col >> 3) ^ (row & 7);
        Hs[row * FIN + sp * 8 + (col & 7)] = f2bf(acc[mi][ni][j]);
      }
    }
  }

  // ---- linear: acc2 = Hs @ W, W^T staged in K-quarters of [256][64] ----
  f32x4 acc2[MI][4] = {};
  for (int qt = 0; qt < NQT; ++qt) {
    __syncthreads();  // Hs visible / previous quarter's Ws reads done
#pragma unroll
    for (int i = 0; i < 4; ++i) {
      int jj = i * 512 + t;
      int h = jj >> 3, s = jj & 7, sp = s ^ (h & 7);
      gld_lds16(WT + (size_t)h * FIN + qt * 64 + sp * 8, Ws + (i * 512 + wid * 64) * 8);
    }
    __syncthreads();
#pragma unroll
    for (int kh = 0; kh < 2; ++kh) {
      bf16x8 hf[MI], wf[4];
#pragma unroll
      for (int mi = 0; mi < MI; ++mi) {
        int row = wr * (BM / 2) + mi * 16 + lr;
        int slotk = qt * 8 + kh * 4 + q;
        int sp = slotk ^ (row & 7);
        hf[mi] = *(const bf16x8*)&Hs[row * FIN + sp * 8];
      }
#pragma unroll
      for (int ni = 0; ni < 4; ++ni) {
        int h = wc * 64 + ni * 16 + lr;
        int sp = (kh * 4 + q) ^ (h & 7);
        wf[ni] = *(const bf16x8*)&Ws[(h * 8 + sp) * 8];
      }
#pragma unroll
      for (int mi = 0; mi < MI; ++mi) {
#pragma unroll
        for (int ni = 0; ni < 4; ++ni)
          acc2[mi][ni] = __builtin_amdgcn_mfma_f32_16x16x32_bf16(hf[mi], wf[ni], acc2[mi][ni], 0, 0, 0);
      }
    }
  }
  __syncthreads();  // all Hs/Ws reads done before redp overlay goes live

  // ---- bias + LayerNorm(256) + relu ----
  float bcol[4], gcol[4], zcol[4];
#pragma unroll
  for (int ni = 0; ni < 4; ++ni) {
    int col = wc * 64 + ni * 16 + lr;
    bcol[ni] = bias[col]; gcol[ni] = gamma[col]; zcol[ni] = beta[col];
  }
#pragma unroll
  for (int mi = 0; mi < MI; ++mi) {
#pragma unroll
    for (int j = 0; j < 4; ++j) {
      float s = 0.f, ss = 0.f;
#pragma unroll
      for (int ni = 0; ni < 4; ++ni) {
        float v = acc2[mi][ni][j] + bcol[ni];
        acc2[mi][ni][j] = v;
        s += v; ss += v * v;
      }
#pragma unroll
      for (int m = 1; m < 16; m <<= 1) { s += __shfl_xor(s, m); ss += __shfl_xor(ss, m); }
      if (lr == 0) {
        int rl = wr * (BM / 2) + mi * 16 + q * 4 + j;
        RED(0, rl, wc) = s;
        RED(1, rl, wc) = ss;
      }
    }
  }
  __syncthreads();
#pragma unroll
  for (int mi = 0; mi < MI; ++mi) {
#pragma unroll
    for (int j = 0; j < 4; ++j) {
      int rl = wr * (BM / 2) + mi * 16 + q * 4 + j;
      float s = RED(0, rl, 0) + RED(0, rl, 1) + RED(0, rl, 2) + RED(0, rl, 3);
      float ss = RED(1, rl, 0) + RED(1, rl, 1) + RED(1, rl, 2) + RED(1, rl, 3);
      float mean = s * (1.f / 256.f);
      float var = ss * (1.f / 256.f) - mean * mean;
      float inv = rsqrtf(var + 1e-5f);
#pragma unroll
      for (int ni = 0; ni < 4; ++ni) {
        float v = (acc2[mi][ni][j] - mean) * inv * gcol[ni] + zcol[ni];
        acc2[mi][ni][j] = v > 0.f ? v : 0.f;
      }
    }
  }
  if (MODE == 0) {
#pragma unroll
    for (int mi = 0; mi < MI; ++mi) {
#pragma unroll
      for (int ni = 0; ni < 4; ++ni) {
        int col = wc * 64 + ni * 16 + lr;
        int rowb = m0 + wr * (BM / 2) + mi * 16 + q * 4;
        ushort4 o;
        o.x = f2bf(acc2[mi][ni][0]); o.y = f2bf(acc2[mi][ni][1]);
        o.z = f2bf(acc2[mi][ni][2]); o.w = f2bf(acc2[mi][ni][3]);
        *(ushort4*)(HTout + ((size_t)b * 256 + col) * NN + rowb) = o;
      }
    }
  } else {
#pragma unroll
    for (int ni = 0; ni < 4; ++ni) {
      float cs = 0.f;
#pragma unroll
      for (int mi = 0; mi < MI; ++mi) {
#pragma unroll
        for (int j = 0; j < 4; ++j) cs += acc2[mi][ni][j];
      }
      cs += __shfl_xor(cs, 16);
      cs += __shfl_xor(cs, 32);
      if (q == 0) {
        int col = wc * 64 + ni * 16 + lr;
        gpart[(((size_t)b * NMB + mb) * 2 + wr) * 256 + col] = cs;
      }
    }
  }
}

__global__ void k_readout(const float* __restrict__ gpart, const float* __restrict__ Wa,
                          const float* __restrict__ ba, const float* __restrict__ Wl,
                          const float* __restrict__ bl, float* __restrict__ out) {
  __shared__ float gl[256];
  int b = blockIdx.x, t = threadIdx.x;  // 256 threads
  float s = 0.f;
#pragma unroll 4
  for (int p = 0; p < 64; ++p) s += gpart[((size_t)b * 64 + p) * 256 + t];
  gl[t] = s * (1.f / 2048.f);
  __syncthreads();
  if (t < 128) {
    int k = t & 63;
    const float* W = (t >= 64) ? Wl : Wa;
    const float* bb = (t >= 64) ? bl : ba;
    float a = 0.f;
    for (int h = 0; h < 256; ++h) a += gl[h] * W[h * 64 + k];
    a += bb[k];
    out[((t >= 64) ? 2048 : 0) + b * 64 + k] = a;
  }
}

extern "C" void kernel_launch(void* const* d_in, const int* in_sizes, int n_in,
                              void* d_out, int out_size, void* d_ws, size_t ws_size,
                              hipStream_t stream) {
  const float* A_hat = (const float*)d_in[0];
  const float* X   = (const float*)d_in[1];
  const float* W1  = (const float*)d_in[2];
  const float* b1  = (const float*)d_in[3];
  const float* g1  = (const float*)d_in[4];
  const float* be1 = (const float*)d_in[5];
  const float* W2  = (const float*)d_in[6];
  const float* b2  = (const float*)d_in[7];
  const float* g2  = (const float*)d_in[8];
  const float* be2 = (const float*)d_in[9];
  const float* Wa  = (const float*)d_in[10];
  const float* ba  = (const float*)d_in[11];
  const float* Wl  = (const float*)d_in[12];
  const float* bl  = (const float*)d_in[13];

  char* ws = (char*)d_ws;
  const size_t MB = 1024 * 1024;
  unsigned short* XT  = (unsigned short*)(ws);                         // 16 MiB (B,128,2048)
  unsigned short* H1T = (unsigned short*)(ws + 16 * MB);               // 32 MiB (B,256,2048)
  unsigned short* W1T = (unsigned short*)(ws + 48 * MB);               // 64 KB (256x128)
  unsigned short* W2T = (unsigned short*)(ws + 48 * MB + 256 * 1024);  // 128 KB (256x256)
  float* gpart        = (float*)(ws + 49 * MB);                        // 2 MiB (B,64,256)

  // prep: transposed bf16 copies
  k_tr_cvt<<<dim3(64, 4, 32), 256, 0, stream>>>(X, XT, 2048, 128);
  k_tr_cvt<<<dim3(4, 8, 1), 256, 0, stream>>>(W1, W1T, 128, 256);
  k_tr_cvt<<<dim3(8, 8, 1), 256, 0, stream>>>(W2, W2T, 256, 256);
  // layer 1 fused: H1T = relu(LN(A@X @ W1 + b1))^T   (BM=128, 68->64KB LDS, 2 blk/CU)
  k_agg_fused<128, 128, 0><<<dim3(16, 1, 32), 512, 0, stream>>>(
      A_hat, XT, W1T, b1, g1, be1, H1T, nullptr);
  // layer 2 fused: gpart partials of relu(LN(A@H1 @ W2 + b2))  (BM=64, 80KB LDS, 2 blk/CU)
  k_agg_fused<64, 256, 1><<<dim3(32, 1, 32), 512, 0, stream>>>(
      A_hat, H1T, W2T, b2, g2, be2, nullptr, gpart);
  // readout
  k_readout<<<dim3(32), 256, 0, stream>>>(gpart, Wa, ba, Wl, bl, (float*)d_out);
}

// Round 5
// 332.470 us; speedup vs baseline: 1.1913x; 1.1913x over previous
//
#include <hip/hip_runtime.h>
#include <hip/hip_bf16.h>

#define NN 2048

typedef __attribute__((ext_vector_type(4))) float f32x4;
typedef __attribute__((ext_vector_type(8))) short bf16x8;

__device__ __forceinline__ unsigned short f2bf(float f) {
  __hip_bfloat16 h = __float2bfloat16(f);
  return __builtin_bit_cast(unsigned short, h);
}
__device__ __forceinline__ unsigned int pk2(float a, float b) {
  return (unsigned int)f2bf(a) | ((unsigned int)f2bf(b) << 16);
}
__device__ __forceinline__ void gld_lds16(const void* g, void* l) {
  __builtin_amdgcn_global_load_lds(
      (const __attribute__((address_space(1))) unsigned int*)g,
      (__attribute__((address_space(3))) unsigned int*)l, 16, 0, 0);
}

// f32 (R x C) -> bf16 (C x R), batched via blockIdx.z
__global__ void k_tr_cvt(const float* __restrict__ src, unsigned short* __restrict__ dst,
                         int R, int C) {
  int b = blockIdx.z;
  src += (size_t)b * R * C;
  dst += (size_t)b * R * C;
  __shared__ float tile[32][33];
  int r0 = blockIdx.x * 32, c0 = blockIdx.y * 32;
  int t = threadIdx.x;
  int r = t >> 3, c4 = (t & 7) << 2;
  float4 v = *(const float4*)(src + (size_t)(r0 + r) * C + c0 + c4);
  tile[r][c4 + 0] = v.x; tile[r][c4 + 1] = v.y; tile[r][c4 + 2] = v.z; tile[r][c4 + 3] = v.w;
  __syncthreads();
  ushort4 o;
  o.x = f2bf(tile[c4 + 0][r]); o.y = f2bf(tile[c4 + 1][r]);
  o.z = f2bf(tile[c4 + 2][r]); o.w = f2bf(tile[c4 + 3][r]);
  *(ushort4*)(dst + (size_t)(c0 + r) * R + r0 + c4) = o;
}

// Fused: T = A[b] (NNxNN f32) @ B[b] (BT given, NCOLS x NN bf16), then
// out = relu(LN(T @ W + bias)) with W^T given (256 x NCOLS bf16).
// MODE 0: write out^T (b,256,NN); MODE 1: per-block column partials -> gpart.
// 512 threads, 8 waves (2 wr x 4 wc). Main: BM=128, BN=NCOLS, BK=64,
// depth-2 f32->bf16 A prefetch, 1 barrier/K-step.  (R3 structure, verbatim.)
#define AGG_STEP(KT, AREGC, AREGN, CUR)                                        \
  {                                                                            \
    const int kt_ = (KT);                                                      \
    if (kt_ < NKT - 2) { /* issue A loads for kt+2 */                          \
      const float* p_ = apb + (size_t)(kt_ + 2) * 64;                          \
      _Pragma("unroll") for (int j = 0; j < 4; ++j)                            \
          AREGN[j] = ((const float4*)p_)[j];                                   \
    }                                                                          \
    if (kt_ < NKT - 1) {                                                       \
      _Pragma("unroll") for (int i = 0; i < NF; ++i) { /* B tile kt+1 */       \
        int jj = i * 512 + t;                                                  \
        int n_ = jj >> 3, s_ = jj & 7, sp_ = s_ ^ (n_ & 7);                    \
        gld_lds16(BTb + (size_t)n_ * NN + (size_t)(kt_ + 1) * 64 + sp_ * 8,    \
                  &Bs[(CUR) ^ 1][(i * 512 + wid * 64) * 8]);                   \
      }                                                                        \
      _Pragma("unroll") for (int i = 0; i < 2; ++i) { /* cvt A tile kt+1 */    \
        uint4 w_;                                                              \
        w_.x = pk2(AREGC[2 * i].x, AREGC[2 * i].y);                            \
        w_.y = pk2(AREGC[2 * i].z, AREGC[2 * i].w);                            \
        w_.z = pk2(AREGC[2 * i + 1].x, AREGC[2 * i + 1].y);                    \
        w_.w = pk2(AREGC[2 * i + 1].z, AREGC[2 * i + 1].w);                    \
        int s_ = ak * 2 + i, sp_ = s_ ^ (ar & 7);                              \
        *(uint4*)&As[(CUR) ^ 1][(ar * 8 + sp_) * 8] = w_;                      \
      }                                                                        \
    }                                                                          \
    _Pragma("unroll") for (int kh = 0; kh < 2; ++kh) {                         \
      bf16x8 af[4], bfr[NF];                                                   \
      _Pragma("unroll") for (int mi = 0; mi < 4; ++mi) {                       \
        int row = wr * 64 + mi * 16 + lr;                                      \
        int sp_ = (kh * 4 + q) ^ (row & 7);                                    \
        af[mi] = *(const bf16x8*)&As[CUR][(row * 8 + sp_) * 8];                \
      }                                                                        \
      _Pragma("unroll") for (int ni = 0; ni < NF; ++ni) {                      \
        int brow = wc * WN + ni * 16 + lr;                                     \
        int sp_ = (kh * 4 + q) ^ (brow & 7);                                   \
        bfr[ni] = *(const bf16x8*)&Bs[CUR][(brow * 8 + sp_) * 8];              \
      }                                                                        \
      _Pragma("unroll") for (int mi = 0; mi < 4; ++mi)                         \
        _Pragma("unroll") for (int ni = 0; ni < NF; ++ni)                      \
          acc[mi][ni] = __builtin_amdgcn_mfma_f32_16x16x32_bf16(               \
              af[mi], bfr[ni], acc[mi][ni], 0, 0, 0);                          \
    }                                                                          \
    __syncthreads();                                                           \
  }

template <int NCOLS, int MODE>
__global__ __launch_bounds__(512, NCOLS == 128 ? 4 : 2) void k_agg_fused(
    const float* __restrict__ A, const unsigned short* __restrict__ BT,
    const unsigned short* __restrict__ WT, const float* __restrict__ bias,
    const float* __restrict__ gamma, const float* __restrict__ beta,
    unsigned short* __restrict__ HTout, float* __restrict__ gpart) {
  constexpr int WN = NCOLS / 4;   // wave n-width in main loop
  constexpr int NF = NCOLS / 64;  // b-frag count / B-stage iters
  constexpr int NKT = NN / 64;    // 32 K-steps
  constexpr int FIN = NCOLS;      // K of the fused linear
  constexpr int NQT = FIN / 64;   // epilogue K-quarters
  constexpr int NMB = NN / 128;   // m-blocks per batch (16)

  __shared__ __align__(16) unsigned short As[2][128 * 64];
  __shared__ __align__(16) unsigned short Bs[2][NCOLS * 64];
  __shared__ float red[2][128][4];

  // XCD-aware swizzle (ONLY change vs R3): HW assigns linear block id L to
  // XCD L%8; map so all blocks of one batch (sharing the BT panel) land on
  // one XCD and are contiguous in dispatch order. Bijective: grid = 512.
  int L = blockIdx.x + gridDim.x * blockIdx.z;
  int xcd = L & 7, slot = L >> 3;
  int mb = slot % NMB;
  int b = xcd + 8 * (slot / NMB);
  int m0 = mb * 128;

  const float* Ab = A + (size_t)b * NN * NN;
  const unsigned short* BTb = BT + (size_t)b * (size_t)NCOLS * NN;
  int t = threadIdx.x, lane = t & 63, wid = t >> 6;
  int wr = wid >> 2, wc = wid & 3;
  int q = lane >> 4, lr = lane & 15;
  int ar = t >> 2, ak = t & 3;  // A staging: row, 16-f32 chunk
  const float* apb = Ab + (size_t)(m0 + ar) * NN + ak * 16;

  f32x4 acc[4][NF] = {};
  float4 aregA[4], aregB[4];

  // prologue: tile0 -> buf0; issue tile1 A loads
  {
#pragma unroll
    for (int j = 0; j < 4; ++j) aregA[j] = ((const float4*)apb)[j];
#pragma unroll
    for (int i = 0; i < NF; ++i) {
      int jj = i * 512 + t;
      int n = jj >> 3, s = jj & 7, sp = s ^ (n & 7);
      gld_lds16(BTb + (size_t)n * NN + sp * 8, &Bs[0][(i * 512 + wid * 64) * 8]);
    }
#pragma unroll
    for (int i = 0; i < 2; ++i) {
      uint4 w;
      w.x = pk2(aregA[2 * i].x, aregA[2 * i].y);
      w.y = pk2(aregA[2 * i].z, aregA[2 * i].w);
      w.z = pk2(aregA[2 * i + 1].x, aregA[2 * i + 1].y);
      w.w = pk2(aregA[2 * i + 1].z, aregA[2 * i + 1].w);
      int s = ak * 2 + i, sp = s ^ (ar & 7);
      *(uint4*)&As[0][(ar * 8 + sp) * 8] = w;
    }
#pragma unroll
    for (int j = 0; j < 4; ++j) aregB[j] = ((const float4*)(apb + 64))[j];
  }
  __syncthreads();

  for (int k2 = 0; k2 < NKT / 2; ++k2) {
    AGG_STEP(2 * k2, aregB, aregA, 0);
    AGG_STEP(2 * k2 + 1, aregA, aregB, 1);
  }

  // ---- epilogue: T(128 x FIN) -> bf16 Hs in LDS (swizzled) ----
  unsigned short* Hs = (NCOLS == 128) ? &As[0][0] : &Bs[0][0];
  unsigned short* Ws = (NCOLS == 128) ? &Bs[0][0] : &As[0][0];
#pragma unroll
  for (int mi = 0; mi < 4; ++mi) {
#pragma unroll
    for (int ni = 0; ni < NF; ++ni) {
#pragma unroll
      for (int j = 0; j < 4; ++j) {
        int row = wr * 64 + mi * 16 + q * 4 + j;
        int col = wc * WN + ni * 16 + lr;
        int sp = (col >> 3) ^ (row & 7);
        Hs[row * FIN + sp * 8 + (col & 7)] = f2bf(acc[mi][ni][j]);
      }
    }
  }

  // ---- linear: acc2 = Hs @ W, W^T staged in K-quarters of [256][64] ----
  f32x4 acc2[4][4] = {};
  for (int qt = 0; qt < NQT; ++qt) {
    __syncthreads();  // Hs visible / previous quarter's Ws reads done
#pragma unroll
    for (int i = 0; i < 4; ++i) {
      int jj = i * 512 + t;
      int h = jj >> 3, s = jj & 7, sp = s ^ (h & 7);
      gld_lds16(WT + (size_t)h * FIN + qt * 64 + sp * 8, Ws + (i * 512 + wid * 64) * 8);
    }
    __syncthreads();
#pragma unroll
    for (int kh = 0; kh < 2; ++kh) {
      bf16x8 hf[4], wf[4];
#pragma unroll
      for (int mi = 0; mi < 4; ++mi) {
        int row = wr * 64 + mi * 16 + lr;
        int slotk = qt * 8 + kh * 4 + q;
        int sp = slotk ^ (row & 7);
        hf[mi] = *(const bf16x8*)&Hs[row * FIN + sp * 8];
      }
#pragma unroll
      for (int ni = 0; ni < 4; ++ni) {
        int h = wc * 64 + ni * 16 + lr;
        int sp = (kh * 4 + q) ^ (h & 7);
        wf[ni] = *(const bf16x8*)&Ws[(h * 8 + sp) * 8];
      }
#pragma unroll
      for (int mi = 0; mi < 4; ++mi) {
#pragma unroll
        for (int ni = 0; ni < 4; ++ni)
          acc2[mi][ni] = __builtin_amdgcn_mfma_f32_16x16x32_bf16(hf[mi], wf[ni], acc2[mi][ni], 0, 0, 0);
      }
    }
  }

  // ---- bias + LayerNorm(256) + relu ----
  float bcol[4], gcol[4], zcol[4];
#pragma unroll
  for (int ni = 0; ni < 4; ++ni) {
    int col = wc * 64 + ni * 16 + lr;
    bcol[ni] = bias[col]; gcol[ni] = gamma[col]; zcol[ni] = beta[col];
  }
#pragma unroll
  for (int mi = 0; mi < 4; ++mi) {
#pragma unroll
    for (int j = 0; j < 4; ++j) {
      float s = 0.f, ss = 0.f;
#pragma unroll
      for (int ni = 0; ni < 4; ++ni) {
        float v = acc2[mi][ni][j] + bcol[ni];
        acc2[mi][ni][j] = v;
        s += v; ss += v * v;
      }
#pragma unroll
      for (int m = 1; m < 16; m <<= 1) { s += __shfl_xor(s, m); ss += __shfl_xor(ss, m); }
      if (lr == 0) {
        int rl = wr * 64 + mi * 16 + q * 4 + j;
        red[0][rl][wc] = s;
        red[1][rl][wc] = ss;
      }
    }
  }
  __syncthreads();
#pragma unroll
  for (int mi = 0; mi < 4; ++mi) {
#pragma unroll
    for (int j = 0; j < 4; ++j) {
      int rl = wr * 64 + mi * 16 + q * 4 + j;
      float s = red[0][rl][0] + red[0][rl][1] + red[0][rl][2] + red[0][rl][3];
      float ss = red[1][rl][0] + red[1][rl][1] + red[1][rl][2] + red[1][rl][3];
      float mean = s * (1.f / 256.f);
      float var = ss * (1.f / 256.f) - mean * mean;
      float inv = rsqrtf(var + 1e-5f);
#pragma unroll
      for (int ni = 0; ni < 4; ++ni) {
        float v = (acc2[mi][ni][j] - mean) * inv * gcol[ni] + zcol[ni];
        acc2[mi][ni][j] = v > 0.f ? v : 0.f;
      }
    }
  }
  if (MODE == 0) {
#pragma unroll
    for (int mi = 0; mi < 4; ++mi) {
#pragma unroll
      for (int ni = 0; ni < 4; ++ni) {
        int col = wc * 64 + ni * 16 + lr;
        int rowb = m0 + wr * 64 + mi * 16 + q * 4;
        ushort4 o;
        o.x = f2bf(acc2[mi][ni][0]); o.y = f2bf(acc2[mi][ni][1]);
        o.z = f2bf(acc2[mi][ni][2]); o.w = f2bf(acc2[mi][ni][3]);
        *(ushort4*)(HTout + ((size_t)b * 256 + col) * NN + rowb) = o;
      }
    }
  } else {
#pragma unroll
    for (int ni = 0; ni < 4; ++ni) {
      float cs = 0.f;
#pragma unroll
      for (int mi = 0; mi < 4; ++mi) {
#pragma unroll
        for (int j = 0; j < 4; ++j) cs += acc2[mi][ni][j];
      }
      cs += __shfl_xor(cs, 16);
      cs += __shfl_xor(cs, 32);
      if (q == 0) {
        int col = wc * 64 + ni * 16 + lr;
        gpart[(((size_t)b * NMB + mb) * 2 + wr) * 256 + col] = cs;
      }
    }
  }
}

__global__ void k_readout(const float* __restrict__ gpart, const float* __restrict__ Wa,
                          const float* __restrict__ ba, const float* __restrict__ Wl,
                          const float* __restrict__ bl, float* __restrict__ out) {
  __shared__ float gl[256];
  int b = blockIdx.x, t = threadIdx.x;  // 256 threads
  float s = 0.f;
#pragma unroll 4
  for (int p = 0; p < 32; ++p) s += gpart[((size_t)b * 32 + p) * 256 + t];
  gl[t] = s * (1.f / 2048.f);
  __syncthreads();
  if (t < 128) {
    int k = t & 63;
    const float* W = (t >= 64) ? Wl : Wa;
    const float* bb = (t >= 64) ? bl : ba;
    float a = 0.f;
    for (int h = 0; h < 256; ++h) a += gl[h] * W[h * 64 + k];
    a += bb[k];
    out[((t >= 64) ? 2048 : 0) + b * 64 + k] = a;
  }
}

extern "C" void kernel_launch(void* const* d_in, const int* in_sizes, int n_in,
                              void* d_out, int out_size, void* d_ws, size_t ws_size,
                              hipStream_t stream) {
  const float* A_hat = (const float*)d_in[0];
  const float* X   = (const float*)d_in[1];
  const float* W1  = (const float*)d_in[2];
  const float* b1  = (const float*)d_in[3];
  const float* g1  = (const float*)d_in[4];
  const float* be1 = (const float*)d_in[5];
  const float* W2  = (const float*)d_in[6];
  const float* b2  = (const float*)d_in[7];
  const float* g2  = (const float*)d_in[8];
  const float* be2 = (const float*)d_in[9];
  const float* Wa  = (const float*)d_in[10];
  const float* ba  = (const float*)d_in[11];
  const float* Wl  = (const float*)d_in[12];
  const float* bl  = (const float*)d_in[13];

  char* ws = (char*)d_ws;
  const size_t MB = 1024 * 1024;
  unsigned short* XT  = (unsigned short*)(ws);                         // 16 MiB (B,128,2048)
  unsigned short* H1T = (unsigned short*)(ws + 16 * MB);               // 32 MiB (B,256,2048)
  unsigned short* W1T = (unsigned short*)(ws + 48 * MB);               // 64 KB (256x128)
  unsigned short* W2T = (unsigned short*)(ws + 48 * MB + 256 * 1024);  // 128 KB (256x256)
  float* gpart        = (float*)(ws + 49 * MB);                        // 1 MiB (B,32,256)

  // prep: transposed bf16 copies
  k_tr_cvt<<<dim3(64, 4, 32), 256, 0, stream>>>(X, XT, 2048, 128);
  k_tr_cvt<<<dim3(4, 8, 1), 256, 0, stream>>>(W1, W1T, 128, 256);
  k_tr_cvt<<<dim3(8, 8, 1), 256, 0, stream>>>(W2, W2T, 256, 256);
  // layer 1 fused: H1T = relu(LN(A@X @ W1 + b1))^T
  k_agg_fused<128, 0><<<dim3(16, 1, 32), 512, 0, stream>>>(
      A_hat, XT, W1T, b1, g1, be1, H1T, nullptr);
  // layer 2 fused: gpart partials of relu(LN(A@H1 @ W2 + b2))
  k_agg_fused<256, 1><<<dim3(16, 1, 32), 512, 0, stream>>>(
      A_hat, H1T, W2T, b2, g2, be2, nullptr, gpart);
  // readout
  k_readout<<<dim3(32), 256, 0, stream>>>(gpart, Wa, ba, Wl, bl, (float*)d_out);
}